// Round 3
// baseline (980.450 us; speedup 1.0000x reference)
//
#include <hip/hip_runtime.h>
#include <hip/hip_bf16.h>
#include <cstdint>

// CLAM-MIL forward. Inputs/outputs are FLOAT32 (per reference dtypes);
// internal compute uses bf16 MFMA with fp32 accumulation (2% tolerance).
// B=8, N=10000 (M=80000 rows), F=1024, Z=512, C=4.

typedef __bf16 bf16;
typedef __attribute__((ext_vector_type(8))) __bf16 bf16x8;
typedef __attribute__((ext_vector_type(4))) float f32x4;

// ---------------------------------------------------------------------------
// fragment read: 8 contiguous bf16 (16B) = global k-chunk kc of LDS row `row`
// (XOR chunk swizzle: LDS slot c holds global chunk c ^ (row&7))
// ---------------------------------------------------------------------------
__device__ __forceinline__ bf16x8 fragld(const bf16* s, int row, int kc) {
  const int c = kc ^ (row & 7);
  return *(const bf16x8*)(s + row * 64 + c * 8);
}

// stage ROWSx64 bf16 tile (rows k-contiguous) from bf16 global, XOR-swizzled
template <int ROWS>
__device__ __forceinline__ void stage_bf16(const bf16* __restrict__ g, size_t row0,
                                           int ld, int kb, bf16* s, int t) {
#pragma unroll
  for (int i = 0; i < ROWS / 32; ++i) {
    const int r  = i * 32 + (t >> 3);
    const int c  = t & 7;
    const int cg = c ^ (r & 7);
    const bf16x8 v = *(const bf16x8*)(g + (row0 + (size_t)r) * (size_t)ld + (size_t)(kb + cg * 8));
    *(bf16x8*)(s + r * 64 + c * 8) = v;
  }
}

// stage 128x64 tile from FLOAT32 global, converting to bf16, XOR-swizzled
__device__ __forceinline__ void stage_f32(const float* __restrict__ g, size_t row0,
                                          int ld, int kb, bf16* s, int t) {
#pragma unroll
  for (int i = 0; i < 4; ++i) {
    const int r  = i * 32 + (t >> 3);
    const int c  = t & 7;
    const int cg = c ^ (r & 7);
    const float* p = g + (row0 + (size_t)r) * (size_t)ld + (size_t)(kb + cg * 8);
    const float4 a = *(const float4*)(p);
    const float4 b = *(const float4*)(p + 4);
    bf16x8 v;
    v[0] = (bf16)a.x; v[1] = (bf16)a.y; v[2] = (bf16)a.z; v[3] = (bf16)a.w;
    v[4] = (bf16)b.x; v[5] = (bf16)b.y; v[6] = (bf16)b.z; v[7] = (bf16)b.w;
    *(bf16x8*)(s + r * 64 + c * 8) = v;
  }
}

// ---------------------------------------------------------------------------
// 32x32 tiled transpose f32 -> bf16 (weights: <= 2MB each)
// ---------------------------------------------------------------------------
__global__ void transpose_cvt(const float* __restrict__ in, bf16* __restrict__ out,
                              int R, int C) {
  __shared__ float tile[32][33];
  const int bx = blockIdx.x * 32;  // col
  const int by = blockIdx.y * 32;  // row
  const int tx = threadIdx.x, ty = threadIdx.y;  // (32,8)
#pragma unroll
  for (int i = 0; i < 32; i += 8) tile[ty + i][tx] = in[(size_t)(by + ty + i) * C + bx + tx];
  __syncthreads();
#pragma unroll
  for (int i = 0; i < 32; i += 8) out[(size_t)(bx + ty + i) * R + by + tx] = (bf16)tile[tx][ty + i];
}

// ---------------------------------------------------------------------------
// GEMM1: emb = relu(bags[80000,1024](f32) @ W_enc + b_enc) -> bf16 [80000,512]
// Bt = W_enc^T bf16 [512,1024]. 128x256 tile, BK=64. 4 waves: wm in {0,1}
// (64-row half), wn in {0,1} (128-col half); each wave 64x128 = 4x8 frags.
// ---------------------------------------------------------------------------
__global__ __launch_bounds__(256) void gemm_enc(const float* __restrict__ A,
                                                const bf16* __restrict__ Bt,
                                                const float* __restrict__ bias,
                                                bf16* __restrict__ Cout) {
  __shared__ bf16 sA[128 * 64];
  __shared__ bf16 sB[256 * 64];
  const int t = threadIdx.x;
  const int lane = t & 63, wave = t >> 6;
  const int wm = wave >> 1, wn = wave & 1;
  const size_t m0 = (size_t)blockIdx.x * 128;
  const int n0 = blockIdx.y * 256;
  const int lm = lane & 15, lq = lane >> 4;

  f32x4 acc[4][8];
#pragma unroll
  for (int i = 0; i < 4; ++i)
#pragma unroll
    for (int j = 0; j < 8; ++j) acc[i][j] = f32x4{0.f, 0.f, 0.f, 0.f};

  for (int kb = 0; kb < 1024; kb += 64) {
    stage_f32(A, m0, 1024, kb, sA, t);
    stage_bf16<256>(Bt, (size_t)n0, 1024, kb, sB, t);
    __syncthreads();
#pragma unroll
    for (int kk = 0; kk < 2; ++kk) {
      bf16x8 af[4];
#pragma unroll
      for (int mi = 0; mi < 4; ++mi) af[mi] = fragld(sA, wm * 64 + mi * 16 + lm, kk * 4 + lq);
#pragma unroll
      for (int ni = 0; ni < 8; ++ni) {
        const bf16x8 bfr = fragld(sB, wn * 128 + ni * 16 + lm, kk * 4 + lq);
#pragma unroll
        for (int mi = 0; mi < 4; ++mi)
          acc[mi][ni] = __builtin_amdgcn_mfma_f32_16x16x32_bf16(af[mi], bfr, acc[mi][ni], 0, 0, 0);
      }
    }
    __syncthreads();
  }

  // epilogue: bias + relu, store bf16. D layout: col=lane&15, row=lq*4+reg.
#pragma unroll
  for (int ni = 0; ni < 8; ++ni) {
    const int n_g = n0 + wn * 128 + ni * 16 + lm;
    const float bz = bias[n_g];
#pragma unroll
    for (int mi = 0; mi < 4; ++mi) {
#pragma unroll
      for (int r = 0; r < 4; ++r) {
        const size_t m_g = m0 + (size_t)(wm * 64 + mi * 16 + lq * 4 + r);
        const float v = acc[mi][ni][r] + bz;
        Cout[m_g * 512 + n_g] = (bf16)fmaxf(v, 0.f);
      }
    }
  }
}

// ---------------------------------------------------------------------------
// GEMM2 (fused gate + attention logits):
//   hu = emb@W_u + b_u ; hv = emb@W_v + b_v ; g = sigmoid(hu)*tanh(hv)
//   logits[m,c] += sum_z g[m,z] * W_attn[c,z]   (fp32 atomics, partial over z)
// Dual-B GEMM sharing the A tile. K=512. emb is bf16 (ws); biases/Wa are f32.
// ---------------------------------------------------------------------------
__global__ __launch_bounds__(256) void gemm_gate(const bf16* __restrict__ A,
                                                 const bf16* __restrict__ But,
                                                 const bf16* __restrict__ Bvt,
                                                 const float* __restrict__ bu,
                                                 const float* __restrict__ bv,
                                                 const float* __restrict__ Wa,
                                                 float* __restrict__ logits) {
  __shared__ bf16 sA[128 * 64];
  __shared__ bf16 sU[128 * 64];
  __shared__ bf16 sV[128 * 64];
  const int t = threadIdx.x;
  const int lane = t & 63, wave = t >> 6;
  const int wm = wave >> 1, wn = wave & 1;
  const size_t m0 = (size_t)blockIdx.x * 128;
  const int n0 = blockIdx.y * 128;
  const int lm = lane & 15, lq = lane >> 4;

  f32x4 accU[4][4], accV[4][4];
#pragma unroll
  for (int i = 0; i < 4; ++i)
#pragma unroll
    for (int j = 0; j < 4; ++j) {
      accU[i][j] = f32x4{0.f, 0.f, 0.f, 0.f};
      accV[i][j] = f32x4{0.f, 0.f, 0.f, 0.f};
    }

  for (int kb = 0; kb < 512; kb += 64) {
    stage_bf16<128>(A, m0, 512, kb, sA, t);
    stage_bf16<128>(But, (size_t)n0, 512, kb, sU, t);
    stage_bf16<128>(Bvt, (size_t)n0, 512, kb, sV, t);
    __syncthreads();
#pragma unroll
    for (int kk = 0; kk < 2; ++kk) {
      bf16x8 af[4];
#pragma unroll
      for (int mi = 0; mi < 4; ++mi) af[mi] = fragld(sA, wm * 64 + mi * 16 + lm, kk * 4 + lq);
#pragma unroll
      for (int ni = 0; ni < 4; ++ni) {
        const int row = wn * 64 + ni * 16 + lm;
        const bf16x8 bu8 = fragld(sU, row, kk * 4 + lq);
        const bf16x8 bv8 = fragld(sV, row, kk * 4 + lq);
#pragma unroll
        for (int mi = 0; mi < 4; ++mi)
          accU[mi][ni] = __builtin_amdgcn_mfma_f32_16x16x32_bf16(af[mi], bu8, accU[mi][ni], 0, 0, 0);
#pragma unroll
        for (int mi = 0; mi < 4; ++mi)
          accV[mi][ni] = __builtin_amdgcn_mfma_f32_16x16x32_bf16(af[mi], bv8, accV[mi][ni], 0, 0, 0);
      }
    }
    __syncthreads();
  }

  // epilogue: per-lane column metadata (all f32 inputs)
  float bzu[4], bzv[4], wa[4][4];
#pragma unroll
  for (int ni = 0; ni < 4; ++ni) {
    const int n_g = n0 + wn * 64 + ni * 16 + lm;
    bzu[ni] = bu[n_g];
    bzv[ni] = bv[n_g];
#pragma unroll
    for (int c = 0; c < 4; ++c) wa[ni][c] = Wa[c * 512 + n_g];
  }

#pragma unroll
  for (int mi = 0; mi < 4; ++mi) {
#pragma unroll
    for (int r = 0; r < 4; ++r) {
      float pc[4] = {0.f, 0.f, 0.f, 0.f};
#pragma unroll
      for (int ni = 0; ni < 4; ++ni) {
        const float hu = accU[mi][ni][r] + bzu[ni];
        const float hv = accV[mi][ni][r] + bzv[ni];
        // sigmoid(hu) * tanh(hv); overflow-safe: exp->inf => 2/(1+inf)=0
        const float sg = 1.f / (1.f + __expf(-hu));
        const float th = 1.f - 2.f / (1.f + __expf(2.f * hv));
        const float g = sg * th;
#pragma unroll
        for (int c = 0; c < 4; ++c) pc[c] += g * wa[ni][c];
      }
      // reduce over the 16 lanes sharing this output row (lane bits 0..3)
#pragma unroll
      for (int o = 8; o >= 1; o >>= 1) {
#pragma unroll
        for (int c = 0; c < 4; ++c) pc[c] += __shfl_xor(pc[c], o);
      }
      if (lm == 0) {
        const size_t m_g = m0 + (size_t)(wm * 64 + mi * 16 + lq * 4 + r);
#pragma unroll
        for (int c = 0; c < 4; ++c) atomicAdd(&logits[m_g * 4 + c], pc[c]);
      }
    }
  }
}

// ---------------------------------------------------------------------------
// softmax over N per (b,c); rewrites logits buffer in place with attn weights.
// b_attn omitted: constant shift per (b,c) cancels in softmax.
// ---------------------------------------------------------------------------
__global__ void softmax_attn(float* __restrict__ logits) {
  const int b = blockIdx.x >> 2, c = blockIdx.x & 3;
  float* base = logits + (size_t)b * 10000 * 4 + c;
  const int t = threadIdx.x;
  const int lane = t & 63, w = t >> 6;
  __shared__ float red[8];

  float m = -3.0e38f;
  for (int n = t; n < 10000; n += 256) m = fmaxf(m, base[(size_t)n * 4]);
#pragma unroll
  for (int o = 32; o >= 1; o >>= 1) m = fmaxf(m, __shfl_xor(m, o));
  if (lane == 0) red[w] = m;
  __syncthreads();
  m = fmaxf(fmaxf(red[0], red[1]), fmaxf(red[2], red[3]));

  float s = 0.f;
  for (int n = t; n < 10000; n += 256) s += __expf(base[(size_t)n * 4] - m);
#pragma unroll
  for (int o = 32; o >= 1; o >>= 1) s += __shfl_xor(s, o);
  if (lane == 0) red[4 + w] = s;
  __syncthreads();
  s = red[4] + red[5] + red[6] + red[7];

  const float rs = 1.f / s;
  for (int n = t; n < 10000; n += 256) base[(size_t)n * 4] = __expf(base[(size_t)n * 4] - m) * rs;
}

// ---------------------------------------------------------------------------
// scores[b,c] = sum_n attn[b,n,c] * (emb[b,n,:] . W_cls[c,:])
// block = (b, chunk of 250 rows); 4 waves, wave-per-row round robin.
// ---------------------------------------------------------------------------
__global__ __launch_bounds__(256) void scores_partial(const bf16* __restrict__ emb,
                                                      const float* __restrict__ attn,
                                                      const float* __restrict__ Wcls,
                                                      float* __restrict__ sacc) {
  const int b = blockIdx.x;
  const int chunk = blockIdx.y;
  const int t = threadIdx.x;
  const int wave = t >> 6, lane = t & 63;

  float wcl[4][8];
#pragma unroll
  for (int c = 0; c < 4; ++c) {
    const float4 wlo = *(const float4*)(Wcls + c * 512 + lane * 8);
    const float4 whi = *(const float4*)(Wcls + c * 512 + lane * 8 + 4);
    wcl[c][0] = wlo.x; wcl[c][1] = wlo.y; wcl[c][2] = wlo.z; wcl[c][3] = wlo.w;
    wcl[c][4] = whi.x; wcl[c][5] = whi.y; wcl[c][6] = whi.z; wcl[c][7] = whi.w;
  }

  float acc[4] = {0.f, 0.f, 0.f, 0.f};
  const int nbeg = chunk * 250, nend = nbeg + 250;
  for (int n = nbeg + wave; n < nend; n += 4) {
    const size_t row = (size_t)b * 10000 + n;
    const bf16x8 e8 = *(const bf16x8*)(emb + row * 512 + lane * 8);
    float d[4] = {0.f, 0.f, 0.f, 0.f};
#pragma unroll
    for (int j = 0; j < 8; ++j) {
      const float e = (float)e8[j];
#pragma unroll
      for (int c = 0; c < 4; ++c) d[c] += e * wcl[c][j];
    }
#pragma unroll
    for (int o = 32; o >= 1; o >>= 1) {
#pragma unroll
      for (int c = 0; c < 4; ++c) d[c] += __shfl_xor(d[c], o);
    }
    const float4 wv = *(const float4*)(attn + row * 4);
    acc[0] += wv.x * d[0];
    acc[1] += wv.y * d[1];
    acc[2] += wv.z * d[2];
    acc[3] += wv.w * d[3];
  }
  if (lane == 0) {
#pragma unroll
    for (int c = 0; c < 4; ++c) atomicAdd(&sacc[b * 4 + c], acc[c]);
  }
}

__global__ void finalize(const float* __restrict__ sacc, const float* __restrict__ b_cls,
                         float* __restrict__ out) {
  const int i = threadIdx.x;
  if (i < 32) out[i] = sacc[i] + b_cls[i & 3];
}

// ---------------------------------------------------------------------------
extern "C" void kernel_launch(void* const* d_in, const int* in_sizes, int n_in,
                              void* d_out, int out_size, void* d_ws, size_t ws_size,
                              hipStream_t stream) {
  (void)in_sizes; (void)n_in; (void)out_size; (void)ws_size;
  const float* bags   = (const float*)d_in[0];
  const float* W_enc  = (const float*)d_in[1];
  const float* b_enc  = (const float*)d_in[2];
  const float* W_u    = (const float*)d_in[3];
  const float* b_u    = (const float*)d_in[4];
  const float* W_v    = (const float*)d_in[5];
  const float* b_v    = (const float*)d_in[6];
  const float* W_attn = (const float*)d_in[7];
  // d_in[8] = b_attn: unused (cancels in softmax over instances)
  const float* W_cls  = (const float*)d_in[9];
  const float* b_cls  = (const float*)d_in[10];
  float* out = (float*)d_out;

  char* ws = (char*)d_ws;
  bf16*  emb    = (bf16*)(ws);                       // 80000*512*2  = 81,920,000 B
  float* logits = (float*)(ws + 81920000);           // 80000*4*4   =  1,280,000 B
  bf16*  WencT  = (bf16*)(ws + 83200000);            // 512*1024*2  =  1,048,576 B
  bf16*  WuT    = (bf16*)(ws + 84248576);            // 512*512*2   =    524,288 B
  bf16*  WvT    = (bf16*)(ws + 84772864);            // 512*512*2   =    524,288 B
  float* sacc   = (float*)(ws + 85297152);           // 32*4        =        128 B

  hipMemsetAsync(logits, 0, 80000 * 4 * sizeof(float), stream);
  hipMemsetAsync(sacc, 0, 32 * sizeof(float), stream);

  transpose_cvt<<<dim3(16, 32), dim3(32, 8), 0, stream>>>(W_enc, WencT, 1024, 512);
  transpose_cvt<<<dim3(16, 16), dim3(32, 8), 0, stream>>>(W_u, WuT, 512, 512);
  transpose_cvt<<<dim3(16, 16), dim3(32, 8), 0, stream>>>(W_v, WvT, 512, 512);

  gemm_enc<<<dim3(625, 2), 256, 0, stream>>>(bags, WencT, b_enc, emb);
  gemm_gate<<<dim3(625, 4), 256, 0, stream>>>(emb, WuT, WvT, b_u, b_v, W_attn, logits);
  softmax_attn<<<32, 256, 0, stream>>>(logits);
  scores_partial<<<dim3(8, 40), 256, 0, stream>>>(emb, logits, W_cls, sacc);
  finalize<<<1, 64, 0, stream>>>(sacc, b_cls, out);
}

// Round 4
// 977.118 us; speedup vs baseline: 1.0034x; 1.0034x over previous
//
#include <hip/hip_runtime.h>
#include <hip/hip_bf16.h>
#include <cstdint>

// CLAM-MIL forward. Inputs/outputs FLOAT32; internal compute bf16 MFMA + fp32 accum.
// B=8, N=10000 (M=80000 rows), F=1024, Z=512, C=4.
//
// Round 4: reintroduce async global->LDS DMA staging (global_load_lds width=16)
// for all bf16 tiles (gate: A,Bu,Bv; enc: B). Proven-correct lane mapping:
// per wave, LDS dest = uniform base + lane*16.

typedef __bf16 bf16;
typedef __attribute__((ext_vector_type(8))) __bf16 bf16x8;
typedef __attribute__((ext_vector_type(4))) float f32x4;

#define AS1 __attribute__((address_space(1)))
#define AS3 __attribute__((address_space(3)))

// ---------------------------------------------------------------------------
// fragment read: 8 contiguous bf16 (16B) = global k-chunk kc of LDS row `row`
// (XOR chunk swizzle: LDS slot c holds global chunk c ^ (row&7))
// ---------------------------------------------------------------------------
__device__ __forceinline__ bf16x8 fragld(const bf16* s, int row, int kc) {
  const int c = kc ^ (row & 7);
  return *(const bf16x8*)(s + row * 64 + c * 8);
}

// ---------------------------------------------------------------------------
// async DMA staging: ROWSx64 bf16 tile (rows k-contiguous), XOR-swizzled.
// Global address is per-lane (swizzled fetch); LDS dest is wave-uniform base
// + lane*16 (t*8 bf16 == t*16 bytes). 256 threads, ROWS/32 issues.
// ---------------------------------------------------------------------------
template <int ROWS>
__device__ __forceinline__ void stage_dma(const bf16* __restrict__ g, size_t row0,
                                          int ld, int kb, bf16* s, int t) {
#pragma unroll
  for (int i = 0; i < ROWS / 32; ++i) {
    const int r  = i * 32 + (t >> 3);
    const int c  = t & 7;
    const int cg = c ^ (r & 7);
    const bf16* gp = g + (row0 + (size_t)r) * (size_t)ld + (size_t)(kb + cg * 8);
    bf16* sp = s + i * 2048 + t * 8;  // == r*64 + c*8 elems; per-wave lane*16 bytes
    __builtin_amdgcn_global_load_lds((const AS1 void*)gp, (AS3 void*)sp, 16, 0, 0);
  }
}

// stage 128x64 tile from FLOAT32 global, converting to bf16, XOR-swizzled
__device__ __forceinline__ void stage_f32(const float* __restrict__ g, size_t row0,
                                          int ld, int kb, bf16* s, int t) {
#pragma unroll
  for (int i = 0; i < 4; ++i) {
    const int r  = i * 32 + (t >> 3);
    const int c  = t & 7;
    const int cg = c ^ (r & 7);
    const float* p = g + (row0 + (size_t)r) * (size_t)ld + (size_t)(kb + cg * 8);
    const float4 a = *(const float4*)(p);
    const float4 b = *(const float4*)(p + 4);
    bf16x8 v;
    v[0] = (bf16)a.x; v[1] = (bf16)a.y; v[2] = (bf16)a.z; v[3] = (bf16)a.w;
    v[4] = (bf16)b.x; v[5] = (bf16)b.y; v[6] = (bf16)b.z; v[7] = (bf16)b.w;
    *(bf16x8*)(s + r * 64 + c * 8) = v;
  }
}

// ---------------------------------------------------------------------------
// 32x32 tiled transpose f32 -> bf16 (weights: <= 2MB each)
// ---------------------------------------------------------------------------
__global__ void transpose_cvt(const float* __restrict__ in, bf16* __restrict__ out,
                              int R, int C) {
  __shared__ float tile[32][33];
  const int bx = blockIdx.x * 32;  // col
  const int by = blockIdx.y * 32;  // row
  const int tx = threadIdx.x, ty = threadIdx.y;  // (32,8)
#pragma unroll
  for (int i = 0; i < 32; i += 8) tile[ty + i][tx] = in[(size_t)(by + ty + i) * C + bx + tx];
  __syncthreads();
#pragma unroll
  for (int i = 0; i < 32; i += 8) out[(size_t)(bx + ty + i) * R + by + tx] = (bf16)tile[tx][ty + i];
}

// ---------------------------------------------------------------------------
// GEMM1: emb = relu(bags[80000,1024](f32) @ W_enc + b_enc) -> bf16 [80000,512]
// Bt = W_enc^T bf16 [512,1024]. 128x256 tile, BK=64. 4 waves: wm in {0,1}
// (64-row half), wn in {0,1} (128-col half); each wave 64x128 = 4x8 frags.
// A staged with explicit f32->bf16 convert; B staged via async DMA.
// ---------------------------------------------------------------------------
__global__ __launch_bounds__(256) void gemm_enc(const float* __restrict__ A,
                                                const bf16* __restrict__ Bt,
                                                const float* __restrict__ bias,
                                                bf16* __restrict__ Cout) {
  __shared__ bf16 sA[128 * 64];
  __shared__ bf16 sB[256 * 64];
  const int t = threadIdx.x;
  const int lane = t & 63, wave = t >> 6;
  const int wm = wave >> 1, wn = wave & 1;
  const size_t m0 = (size_t)blockIdx.x * 128;
  const int n0 = blockIdx.y * 256;
  const int lm = lane & 15, lq = lane >> 4;

  f32x4 acc[4][8];
#pragma unroll
  for (int i = 0; i < 4; ++i)
#pragma unroll
    for (int j = 0; j < 8; ++j) acc[i][j] = f32x4{0.f, 0.f, 0.f, 0.f};

  for (int kb = 0; kb < 1024; kb += 64) {
    stage_dma<256>(Bt, (size_t)n0, 1024, kb, sB, t);
    stage_f32(A, m0, 1024, kb, sA, t);
    __syncthreads();
#pragma unroll
    for (int kk = 0; kk < 2; ++kk) {
      bf16x8 af[4];
#pragma unroll
      for (int mi = 0; mi < 4; ++mi) af[mi] = fragld(sA, wm * 64 + mi * 16 + lm, kk * 4 + lq);
#pragma unroll
      for (int ni = 0; ni < 8; ++ni) {
        const bf16x8 bfr = fragld(sB, wn * 128 + ni * 16 + lm, kk * 4 + lq);
#pragma unroll
        for (int mi = 0; mi < 4; ++mi)
          acc[mi][ni] = __builtin_amdgcn_mfma_f32_16x16x32_bf16(af[mi], bfr, acc[mi][ni], 0, 0, 0);
      }
    }
    __syncthreads();
  }

  // epilogue: bias + relu, store bf16. D layout: col=lane&15, row=lq*4+reg.
#pragma unroll
  for (int ni = 0; ni < 8; ++ni) {
    const int n_g = n0 + wn * 128 + ni * 16 + lm;
    const float bz = bias[n_g];
#pragma unroll
    for (int mi = 0; mi < 4; ++mi) {
#pragma unroll
      for (int r = 0; r < 4; ++r) {
        const size_t m_g = m0 + (size_t)(wm * 64 + mi * 16 + lq * 4 + r);
        const float v = acc[mi][ni][r] + bz;
        Cout[m_g * 512 + n_g] = (bf16)fmaxf(v, 0.f);
      }
    }
  }
}

// ---------------------------------------------------------------------------
// GEMM2 (fused gate + attention logits):
//   hu = emb@W_u + b_u ; hv = emb@W_v + b_v ; g = sigmoid(hu)*tanh(hv)
//   logits[m,c] += sum_z g[m,z] * W_attn[c,z]   (fp32 atomics, partial over z)
// Dual-B GEMM sharing the A tile. K=512. All tiles staged via async DMA.
// ---------------------------------------------------------------------------
__global__ __launch_bounds__(256) void gemm_gate(const bf16* __restrict__ A,
                                                 const bf16* __restrict__ But,
                                                 const bf16* __restrict__ Bvt,
                                                 const float* __restrict__ bu,
                                                 const float* __restrict__ bv,
                                                 const float* __restrict__ Wa,
                                                 float* __restrict__ logits) {
  __shared__ bf16 sA[128 * 64];
  __shared__ bf16 sU[128 * 64];
  __shared__ bf16 sV[128 * 64];
  const int t = threadIdx.x;
  const int lane = t & 63, wave = t >> 6;
  const int wm = wave >> 1, wn = wave & 1;
  const size_t m0 = (size_t)blockIdx.x * 128;
  const int n0 = blockIdx.y * 128;
  const int lm = lane & 15, lq = lane >> 4;

  f32x4 accU[4][4], accV[4][4];
#pragma unroll
  for (int i = 0; i < 4; ++i)
#pragma unroll
    for (int j = 0; j < 4; ++j) {
      accU[i][j] = f32x4{0.f, 0.f, 0.f, 0.f};
      accV[i][j] = f32x4{0.f, 0.f, 0.f, 0.f};
    }

  for (int kb = 0; kb < 512; kb += 64) {
    stage_dma<128>(A, m0, 512, kb, sA, t);
    stage_dma<128>(But, (size_t)n0, 512, kb, sU, t);
    stage_dma<128>(Bvt, (size_t)n0, 512, kb, sV, t);
    __syncthreads();
#pragma unroll
    for (int kk = 0; kk < 2; ++kk) {
      bf16x8 af[4];
#pragma unroll
      for (int mi = 0; mi < 4; ++mi) af[mi] = fragld(sA, wm * 64 + mi * 16 + lm, kk * 4 + lq);
#pragma unroll
      for (int ni = 0; ni < 4; ++ni) {
        const int row = wn * 64 + ni * 16 + lm;
        const bf16x8 bu8 = fragld(sU, row, kk * 4 + lq);
        const bf16x8 bv8 = fragld(sV, row, kk * 4 + lq);
#pragma unroll
        for (int mi = 0; mi < 4; ++mi)
          accU[mi][ni] = __builtin_amdgcn_mfma_f32_16x16x32_bf16(af[mi], bu8, accU[mi][ni], 0, 0, 0);
#pragma unroll
        for (int mi = 0; mi < 4; ++mi)
          accV[mi][ni] = __builtin_amdgcn_mfma_f32_16x16x32_bf16(af[mi], bv8, accV[mi][ni], 0, 0, 0);
      }
    }
    __syncthreads();
  }

  // epilogue: per-lane column metadata (all f32 inputs)
  float bzu[4], bzv[4], wa[4][4];
#pragma unroll
  for (int ni = 0; ni < 4; ++ni) {
    const int n_g = n0 + wn * 64 + ni * 16 + lm;
    bzu[ni] = bu[n_g];
    bzv[ni] = bv[n_g];
#pragma unroll
    for (int c = 0; c < 4; ++c) wa[ni][c] = Wa[c * 512 + n_g];
  }

#pragma unroll
  for (int mi = 0; mi < 4; ++mi) {
#pragma unroll
    for (int r = 0; r < 4; ++r) {
      float pc[4] = {0.f, 0.f, 0.f, 0.f};
#pragma unroll
      for (int ni = 0; ni < 4; ++ni) {
        const float hu = accU[mi][ni][r] + bzu[ni];
        const float hv = accV[mi][ni][r] + bzv[ni];
        // sigmoid(hu) * tanh(hv); overflow-safe: exp->inf => 2/(1+inf)=0
        const float sg = 1.f / (1.f + __expf(-hu));
        const float th = 1.f - 2.f / (1.f + __expf(2.f * hv));
        const float g = sg * th;
#pragma unroll
        for (int c = 0; c < 4; ++c) pc[c] += g * wa[ni][c];
      }
      // reduce over the 16 lanes sharing this output row (lane bits 0..3)
#pragma unroll
      for (int o = 8; o >= 1; o >>= 1) {
#pragma unroll
        for (int c = 0; c < 4; ++c) pc[c] += __shfl_xor(pc[c], o);
      }
      if (lm == 0) {
        const size_t m_g = m0 + (size_t)(wm * 64 + mi * 16 + lq * 4 + r);
#pragma unroll
        for (int c = 0; c < 4; ++c) atomicAdd(&logits[m_g * 4 + c], pc[c]);
      }
    }
  }
}

// ---------------------------------------------------------------------------
// softmax over N per (b,c); rewrites logits buffer in place with attn weights.
// b_attn omitted: constant shift per (b,c) cancels in softmax.
// ---------------------------------------------------------------------------
__global__ void softmax_attn(float* __restrict__ logits) {
  const int b = blockIdx.x >> 2, c = blockIdx.x & 3;
  float* base = logits + (size_t)b * 10000 * 4 + c;
  const int t = threadIdx.x;
  const int lane = t & 63, w = t >> 6;
  __shared__ float red[8];

  float m = -3.0e38f;
  for (int n = t; n < 10000; n += 256) m = fmaxf(m, base[(size_t)n * 4]);
#pragma unroll
  for (int o = 32; o >= 1; o >>= 1) m = fmaxf(m, __shfl_xor(m, o));
  if (lane == 0) red[w] = m;
  __syncthreads();
  m = fmaxf(fmaxf(red[0], red[1]), fmaxf(red[2], red[3]));

  float s = 0.f;
  for (int n = t; n < 10000; n += 256) s += __expf(base[(size_t)n * 4] - m);
#pragma unroll
  for (int o = 32; o >= 1; o >>= 1) s += __shfl_xor(s, o);
  if (lane == 0) red[4 + w] = s;
  __syncthreads();
  s = red[4] + red[5] + red[6] + red[7];

  const float rs = 1.f / s;
  for (int n = t; n < 10000; n += 256) base[(size_t)n * 4] = __expf(base[(size_t)n * 4] - m) * rs;
}

// ---------------------------------------------------------------------------
// scores[b,c] = sum_n attn[b,n,c] * (emb[b,n,:] . W_cls[c,:])
// block = (b, chunk of 250 rows); 4 waves, wave-per-row round robin.
// ---------------------------------------------------------------------------
__global__ __launch_bounds__(256) void scores_partial(const bf16* __restrict__ emb,
                                                      const float* __restrict__ attn,
                                                      const float* __restrict__ Wcls,
                                                      float* __restrict__ sacc) {
  const int b = blockIdx.x;
  const int chunk = blockIdx.y;
  const int t = threadIdx.x;
  const int wave = t >> 6, lane = t & 63;

  float wcl[4][8];
#pragma unroll
  for (int c = 0; c < 4; ++c) {
    const float4 wlo = *(const float4*)(Wcls + c * 512 + lane * 8);
    const float4 whi = *(const float4*)(Wcls + c * 512 + lane * 8 + 4);
    wcl[c][0] = wlo.x; wcl[c][1] = wlo.y; wcl[c][2] = wlo.z; wcl[c][3] = wlo.w;
    wcl[c][4] = whi.x; wcl[c][5] = whi.y; wcl[c][6] = whi.z; wcl[c][7] = whi.w;
  }

  float acc[4] = {0.f, 0.f, 0.f, 0.f};
  const int nbeg = chunk * 250, nend = nbeg + 250;
  for (int n = nbeg + wave; n < nend; n += 4) {
    const size_t row = (size_t)b * 10000 + n;
    const bf16x8 e8 = *(const bf16x8*)(emb + row * 512 + lane * 8);
    float d[4] = {0.f, 0.f, 0.f, 0.f};
#pragma unroll
    for (int j = 0; j < 8; ++j) {
      const float e = (float)e8[j];
#pragma unroll
      for (int c = 0; c < 4; ++c) d[c] += e * wcl[c][j];
    }
#pragma unroll
    for (int o = 32; o >= 1; o >>= 1) {
#pragma unroll
      for (int c = 0; c < 4; ++c) d[c] += __shfl_xor(d[c], o);
    }
    const float4 wv = *(const float4*)(attn + row * 4);
    acc[0] += wv.x * d[0];
    acc[1] += wv.y * d[1];
    acc[2] += wv.z * d[2];
    acc[3] += wv.w * d[3];
  }
  if (lane == 0) {
#pragma unroll
    for (int c = 0; c < 4; ++c) atomicAdd(&sacc[b * 4 + c], acc[c]);
  }
}

__global__ void finalize(const float* __restrict__ sacc, const float* __restrict__ b_cls,
                         float* __restrict__ out) {
  const int i = threadIdx.x;
  if (i < 32) out[i] = sacc[i] + b_cls[i & 3];
}

// ---------------------------------------------------------------------------
extern "C" void kernel_launch(void* const* d_in, const int* in_sizes, int n_in,
                              void* d_out, int out_size, void* d_ws, size_t ws_size,
                              hipStream_t stream) {
  (void)in_sizes; (void)n_in; (void)out_size; (void)ws_size;
  const float* bags   = (const float*)d_in[0];
  const float* W_enc  = (const float*)d_in[1];
  const float* b_enc  = (const float*)d_in[2];
  const float* W_u    = (const float*)d_in[3];
  const float* b_u    = (const float*)d_in[4];
  const float* W_v    = (const float*)d_in[5];
  const float* b_v    = (const float*)d_in[6];
  const float* W_attn = (const float*)d_in[7];
  // d_in[8] = b_attn: unused (cancels in softmax over instances)
  const float* W_cls  = (const float*)d_in[9];
  const float* b_cls  = (const float*)d_in[10];
  float* out = (float*)d_out;

  char* ws = (char*)d_ws;
  bf16*  emb    = (bf16*)(ws);                       // 80000*512*2  = 81,920,000 B
  float* logits = (float*)(ws + 81920000);           // 80000*4*4   =  1,280,000 B
  bf16*  WencT  = (bf16*)(ws + 83200000);            // 512*1024*2  =  1,048,576 B
  bf16*  WuT    = (bf16*)(ws + 84248576);            // 512*512*2   =    524,288 B
  bf16*  WvT    = (bf16*)(ws + 84772864);            // 512*512*2   =    524,288 B
  float* sacc   = (float*)(ws + 85297152);           // 32*4        =        128 B

  hipMemsetAsync(logits, 0, 80000 * 4 * sizeof(float), stream);
  hipMemsetAsync(sacc, 0, 32 * sizeof(float), stream);

  transpose_cvt<<<dim3(16, 32), dim3(32, 8), 0, stream>>>(W_enc, WencT, 1024, 512);
  transpose_cvt<<<dim3(16, 16), dim3(32, 8), 0, stream>>>(W_u, WuT, 512, 512);
  transpose_cvt<<<dim3(16, 16), dim3(32, 8), 0, stream>>>(W_v, WvT, 512, 512);

  gemm_enc<<<dim3(625, 2), 256, 0, stream>>>(bags, WencT, b_enc, emb);
  gemm_gate<<<dim3(625, 4), 256, 0, stream>>>(emb, WuT, WvT, b_u, b_v, W_attn, logits);
  softmax_attn<<<32, 256, 0, stream>>>(logits);
  scores_partial<<<dim3(8, 40), 256, 0, stream>>>(emb, logits, W_cls, sacc);
  finalize<<<1, 64, 0, stream>>>(sacc, b_cls, out);
}

// Round 5
// 845.390 us; speedup vs baseline: 1.1598x; 1.1558x over previous
//
#include <hip/hip_runtime.h>
#include <hip/hip_bf16.h>
#include <cstdint>

// CLAM-MIL forward. Inputs/outputs FLOAT32; internal compute bf16 MFMA + fp32 accum.
// B=8, N=10000 (M=80000 rows), F=1024, Z=512, C=4.
//
// Round 5: occupancy fix. R3/R4 ran at 1 wave/SIMD because acc AGPRs (128) +
// arch VGPRs (152) > 256 (unified file). Now: 512-thread blocks, per-wave acc
// = 64 regs, __launch_bounds__(512,2) -> 2 waves/SIMD, 2 blocks/CU.
// Plus dispatch swizzle so sibling N-tiles of the same A rows are adjacent.

typedef __bf16 bf16;
typedef __attribute__((ext_vector_type(8))) __bf16 bf16x8;
typedef __attribute__((ext_vector_type(4))) float f32x4;

#define AS1 __attribute__((address_space(1)))
#define AS3 __attribute__((address_space(3)))

// ---------------------------------------------------------------------------
// fragment read: 8 contiguous bf16 (16B) = global k-chunk kc of LDS row `row`
// (XOR chunk swizzle: LDS slot c holds global chunk c ^ (row&7))
// ---------------------------------------------------------------------------
__device__ __forceinline__ bf16x8 fragld(const bf16* s, int row, int kc) {
  const int c = kc ^ (row & 7);
  return *(const bf16x8*)(s + row * 64 + c * 8);
}

// ---------------------------------------------------------------------------
// async DMA staging (512 threads): ROWSx64 bf16 tile, XOR-swizzled.
// idx = i*512 + t; r = idx>>3, c = idx&7; LDS elem off = r*64+c*8 = idx*8,
// so per wave dest = uniform base + lane*16B (required by global_load_lds).
// ---------------------------------------------------------------------------
template <int ROWS>
__device__ __forceinline__ void stage_dma(const bf16* __restrict__ g, size_t row0,
                                          int ld, int kb, bf16* s, int t) {
#pragma unroll
  for (int i = 0; i < ROWS / 64; ++i) {
    const int r  = i * 64 + (t >> 3);
    const int c  = t & 7;
    const int cg = c ^ (r & 7);
    const bf16* gp = g + (row0 + (size_t)r) * (size_t)ld + (size_t)(kb + cg * 8);
    bf16* sp = s + i * 4096 + t * 8;
    __builtin_amdgcn_global_load_lds((const AS1 void*)gp, (AS3 void*)sp, 16, 0, 0);
  }
}

// stage 128x64 tile from FLOAT32 global (512 threads), cvt to bf16, swizzled
__device__ __forceinline__ void stage_f32(const float* __restrict__ g, size_t row0,
                                          int ld, int kb, bf16* s, int t) {
#pragma unroll
  for (int i = 0; i < 2; ++i) {
    const int r  = i * 64 + (t >> 3);
    const int c  = t & 7;
    const int cg = c ^ (r & 7);
    const float* p = g + (row0 + (size_t)r) * (size_t)ld + (size_t)(kb + cg * 8);
    const float4 a = *(const float4*)(p);
    const float4 b = *(const float4*)(p + 4);
    bf16x8 v;
    v[0] = (bf16)a.x; v[1] = (bf16)a.y; v[2] = (bf16)a.z; v[3] = (bf16)a.w;
    v[4] = (bf16)b.x; v[5] = (bf16)b.y; v[6] = (bf16)b.z; v[7] = (bf16)b.w;
    *(bf16x8*)(s + r * 64 + c * 8) = v;
  }
}

// ---------------------------------------------------------------------------
// 32x32 tiled transpose f32 -> bf16 (weights: <= 2MB each)
// ---------------------------------------------------------------------------
__global__ void transpose_cvt(const float* __restrict__ in, bf16* __restrict__ out,
                              int R, int C) {
  __shared__ float tile[32][33];
  const int bx = blockIdx.x * 32;  // col
  const int by = blockIdx.y * 32;  // row
  const int tx = threadIdx.x, ty = threadIdx.y;  // (32,8)
#pragma unroll
  for (int i = 0; i < 32; i += 8) tile[ty + i][tx] = in[(size_t)(by + ty + i) * C + bx + tx];
  __syncthreads();
#pragma unroll
  for (int i = 0; i < 32; i += 8) out[(size_t)(bx + ty + i) * R + by + tx] = (bf16)tile[tx][ty + i];
}

// ---------------------------------------------------------------------------
// GEMM1: emb = relu(bags[80000,1024](f32) @ W_enc + b_enc) -> bf16 [80000,512]
// Bt = W_enc^T bf16 [512,1024]. Block tile 128x256, BK=64, 512 threads
// (8 waves: wm in {0,1} row-half, wn in {0..3} 64-col strip; wave = 64x64,
// acc[4][4] = 64 regs). Swizzle: n0 = (bx&1)*256 so both N-tiles of the same
// A rows are dispatch-adjacent (A fetched once from HBM).
// ---------------------------------------------------------------------------
__global__ __launch_bounds__(512, 2) void gemm_enc(const float* __restrict__ A,
                                                   const bf16* __restrict__ Bt,
                                                   const float* __restrict__ bias,
                                                   bf16* __restrict__ Cout) {
  __shared__ bf16 sA[128 * 64];
  __shared__ bf16 sB[256 * 64];
  const int t = threadIdx.x;
  const int lane = t & 63, wave = t >> 6;
  const int wm = wave >> 2, wn = wave & 3;
  const int bx = blockIdx.x;
  const size_t m0 = (size_t)(bx >> 1) * 128;
  const int n0 = (bx & 1) * 256;
  const int lm = lane & 15, lq = lane >> 4;

  f32x4 acc[4][4];
#pragma unroll
  for (int i = 0; i < 4; ++i)
#pragma unroll
    for (int j = 0; j < 4; ++j) acc[i][j] = f32x4{0.f, 0.f, 0.f, 0.f};

  for (int kb = 0; kb < 1024; kb += 64) {
    stage_dma<256>(Bt, (size_t)n0, 1024, kb, sB, t);
    stage_f32(A, m0, 1024, kb, sA, t);
    __syncthreads();
#pragma unroll
    for (int kk = 0; kk < 2; ++kk) {
      bf16x8 af[4];
#pragma unroll
      for (int mi = 0; mi < 4; ++mi) af[mi] = fragld(sA, wm * 64 + mi * 16 + lm, kk * 4 + lq);
#pragma unroll
      for (int ni = 0; ni < 4; ++ni) {
        const bf16x8 bfr = fragld(sB, wn * 64 + ni * 16 + lm, kk * 4 + lq);
#pragma unroll
        for (int mi = 0; mi < 4; ++mi)
          acc[mi][ni] = __builtin_amdgcn_mfma_f32_16x16x32_bf16(af[mi], bfr, acc[mi][ni], 0, 0, 0);
      }
    }
    __syncthreads();
  }

  // epilogue: bias + relu, store bf16. D layout: col=lane&15, row=lq*4+reg.
#pragma unroll
  for (int ni = 0; ni < 4; ++ni) {
    const int n_g = n0 + wn * 64 + ni * 16 + lm;
    const float bz = bias[n_g];
#pragma unroll
    for (int mi = 0; mi < 4; ++mi) {
#pragma unroll
      for (int r = 0; r < 4; ++r) {
        const size_t m_g = m0 + (size_t)(wm * 64 + mi * 16 + lq * 4 + r);
        const float v = acc[mi][ni][r] + bz;
        Cout[m_g * 512 + n_g] = (bf16)fmaxf(v, 0.f);
      }
    }
  }
}

// ---------------------------------------------------------------------------
// GEMM2 (fused gate + attention logits):
//   hu = emb@W_u + b_u ; hv = emb@W_v + b_v ; g = sigmoid(hu)*tanh(hv)
//   logits[m,c] += sum_z g[m,z] * W_attn[c,z]   (fp32 atomics, partial over z)
// Block tile 128x128, K=512, 512 threads (8 waves: wm in {0..3} 32-row strip,
// wn in {0,1} 64-col strip; wave = 32x64 of BOTH U and V -> acc 64 regs).
// Swizzle: n0 = (bx&3)*128 so the 4 N-tiles of the same emb rows are
// dispatch-adjacent (emb served from L2/L3 after first fetch).
// ---------------------------------------------------------------------------
__global__ __launch_bounds__(512, 2) void gemm_gate(const bf16* __restrict__ A,
                                                    const bf16* __restrict__ But,
                                                    const bf16* __restrict__ Bvt,
                                                    const float* __restrict__ bu,
                                                    const float* __restrict__ bv,
                                                    const float* __restrict__ Wa,
                                                    float* __restrict__ logits) {
  __shared__ bf16 sA[128 * 64];
  __shared__ bf16 sU[128 * 64];
  __shared__ bf16 sV[128 * 64];
  const int t = threadIdx.x;
  const int lane = t & 63, wave = t >> 6;
  const int wm = wave >> 1, wn = wave & 1;
  const int bx = blockIdx.x;
  const size_t m0 = (size_t)(bx >> 2) * 128;
  const int n0 = (bx & 3) * 128;
  const int lm = lane & 15, lq = lane >> 4;

  f32x4 accU[2][4], accV[2][4];
#pragma unroll
  for (int i = 0; i < 2; ++i)
#pragma unroll
    for (int j = 0; j < 4; ++j) {
      accU[i][j] = f32x4{0.f, 0.f, 0.f, 0.f};
      accV[i][j] = f32x4{0.f, 0.f, 0.f, 0.f};
    }

  for (int kb = 0; kb < 512; kb += 64) {
    stage_dma<128>(A, m0, 512, kb, sA, t);
    stage_dma<128>(But, (size_t)n0, 512, kb, sU, t);
    stage_dma<128>(Bvt, (size_t)n0, 512, kb, sV, t);
    __syncthreads();
#pragma unroll
    for (int kk = 0; kk < 2; ++kk) {
      bf16x8 af[2];
#pragma unroll
      for (int mi = 0; mi < 2; ++mi) af[mi] = fragld(sA, wm * 32 + mi * 16 + lm, kk * 4 + lq);
#pragma unroll
      for (int ni = 0; ni < 4; ++ni) {
        const int row = wn * 64 + ni * 16 + lm;
        const bf16x8 bu8 = fragld(sU, row, kk * 4 + lq);
        const bf16x8 bv8 = fragld(sV, row, kk * 4 + lq);
#pragma unroll
        for (int mi = 0; mi < 2; ++mi)
          accU[mi][ni] = __builtin_amdgcn_mfma_f32_16x16x32_bf16(af[mi], bu8, accU[mi][ni], 0, 0, 0);
#pragma unroll
        for (int mi = 0; mi < 2; ++mi)
          accV[mi][ni] = __builtin_amdgcn_mfma_f32_16x16x32_bf16(af[mi], bv8, accV[mi][ni], 0, 0, 0);
      }
    }
    __syncthreads();
  }

  // epilogue: per-lane column metadata (all f32 inputs)
  float bzu[4], bzv[4], wa[4][4];
#pragma unroll
  for (int ni = 0; ni < 4; ++ni) {
    const int n_g = n0 + wn * 64 + ni * 16 + lm;
    bzu[ni] = bu[n_g];
    bzv[ni] = bv[n_g];
#pragma unroll
    for (int c = 0; c < 4; ++c) wa[ni][c] = Wa[c * 512 + n_g];
  }

#pragma unroll
  for (int mi = 0; mi < 2; ++mi) {
#pragma unroll
    for (int r = 0; r < 4; ++r) {
      float pc[4] = {0.f, 0.f, 0.f, 0.f};
#pragma unroll
      for (int ni = 0; ni < 4; ++ni) {
        const float hu = accU[mi][ni][r] + bzu[ni];
        const float hv = accV[mi][ni][r] + bzv[ni];
        // sigmoid(hu) * tanh(hv); rcp approx ok within 2% tol; inf-safe.
        const float sg = __builtin_amdgcn_rcpf(1.f + __expf(-hu));
        const float th = 1.f - 2.f * __builtin_amdgcn_rcpf(1.f + __expf(2.f * hv));
        const float g = sg * th;
#pragma unroll
        for (int c = 0; c < 4; ++c) pc[c] += g * wa[ni][c];
      }
      // reduce over the 16 lanes sharing this output row (lane bits 0..3)
#pragma unroll
      for (int o = 8; o >= 1; o >>= 1) {
#pragma unroll
        for (int c = 0; c < 4; ++c) pc[c] += __shfl_xor(pc[c], o);
      }
      if (lm == 0) {
        const size_t m_g = m0 + (size_t)(wm * 32 + mi * 16 + lq * 4 + r);
#pragma unroll
        for (int c = 0; c < 4; ++c) atomicAdd(&logits[m_g * 4 + c], pc[c]);
      }
    }
  }
}

// ---------------------------------------------------------------------------
// softmax over N per (b,c); rewrites logits buffer in place with attn weights.
// b_attn omitted: constant shift per (b,c) cancels in softmax.
// ---------------------------------------------------------------------------
__global__ void softmax_attn(float* __restrict__ logits) {
  const int b = blockIdx.x >> 2, c = blockIdx.x & 3;
  float* base = logits + (size_t)b * 10000 * 4 + c;
  const int t = threadIdx.x;
  const int lane = t & 63, w = t >> 6;
  __shared__ float red[8];

  float m = -3.0e38f;
  for (int n = t; n < 10000; n += 256) m = fmaxf(m, base[(size_t)n * 4]);
#pragma unroll
  for (int o = 32; o >= 1; o >>= 1) m = fmaxf(m, __shfl_xor(m, o));
  if (lane == 0) red[w] = m;
  __syncthreads();
  m = fmaxf(fmaxf(red[0], red[1]), fmaxf(red[2], red[3]));

  float s = 0.f;
  for (int n = t; n < 10000; n += 256) s += __expf(base[(size_t)n * 4] - m);
#pragma unroll
  for (int o = 32; o >= 1; o >>= 1) s += __shfl_xor(s, o);
  if (lane == 0) red[4 + w] = s;
  __syncthreads();
  s = red[4] + red[5] + red[6] + red[7];

  const float rs = 1.f / s;
  for (int n = t; n < 10000; n += 256) base[(size_t)n * 4] = __expf(base[(size_t)n * 4] - m) * rs;
}

// ---------------------------------------------------------------------------
// scores[b,c] = sum_n attn[b,n,c] * (emb[b,n,:] . W_cls[c,:])
// block = (b, chunk of 250 rows); 4 waves, wave-per-row round robin.
// ---------------------------------------------------------------------------
__global__ __launch_bounds__(256) void scores_partial(const bf16* __restrict__ emb,
                                                      const float* __restrict__ attn,
                                                      const float* __restrict__ Wcls,
                                                      float* __restrict__ sacc) {
  const int b = blockIdx.x;
  const int chunk = blockIdx.y;
  const int t = threadIdx.x;
  const int wave = t >> 6, lane = t & 63;

  float wcl[4][8];
#pragma unroll
  for (int c = 0; c < 4; ++c) {
    const float4 wlo = *(const float4*)(Wcls + c * 512 + lane * 8);
    const float4 whi = *(const float4*)(Wcls + c * 512 + lane * 8 + 4);
    wcl[c][0] = wlo.x; wcl[c][1] = wlo.y; wcl[c][2] = wlo.z; wcl[c][3] = wlo.w;
    wcl[c][4] = whi.x; wcl[c][5] = whi.y; wcl[c][6] = whi.z; wcl[c][7] = whi.w;
  }

  float acc[4] = {0.f, 0.f, 0.f, 0.f};
  const int nbeg = chunk * 250, nend = nbeg + 250;
  for (int n = nbeg + wave; n < nend; n += 4) {
    const size_t row = (size_t)b * 10000 + n;
    const bf16x8 e8 = *(const bf16x8*)(emb + row * 512 + lane * 8);
    float d[4] = {0.f, 0.f, 0.f, 0.f};
#pragma unroll
    for (int j = 0; j < 8; ++j) {
      const float e = (float)e8[j];
#pragma unroll
      for (int c = 0; c < 4; ++c) d[c] += e * wcl[c][j];
    }
#pragma unroll
    for (int o = 32; o >= 1; o >>= 1) {
#pragma unroll
      for (int c = 0; c < 4; ++c) d[c] += __shfl_xor(d[c], o);
    }
    const float4 wv = *(const float4*)(attn + row * 4);
    acc[0] += wv.x * d[0];
    acc[1] += wv.y * d[1];
    acc[2] += wv.z * d[2];
    acc[3] += wv.w * d[3];
  }
  if (lane == 0) {
#pragma unroll
    for (int c = 0; c < 4; ++c) atomicAdd(&sacc[b * 4 + c], acc[c]);
  }
}

__global__ void finalize(const float* __restrict__ sacc, const float* __restrict__ b_cls,
                         float* __restrict__ out) {
  const int i = threadIdx.x;
  if (i < 32) out[i] = sacc[i] + b_cls[i & 3];
}

// ---------------------------------------------------------------------------
extern "C" void kernel_launch(void* const* d_in, const int* in_sizes, int n_in,
                              void* d_out, int out_size, void* d_ws, size_t ws_size,
                              hipStream_t stream) {
  (void)in_sizes; (void)n_in; (void)out_size; (void)ws_size;
  const float* bags   = (const float*)d_in[0];
  const float* W_enc  = (const float*)d_in[1];
  const float* b_enc  = (const float*)d_in[2];
  const float* W_u    = (const float*)d_in[3];
  const float* b_u    = (const float*)d_in[4];
  const float* W_v    = (const float*)d_in[5];
  const float* b_v    = (const float*)d_in[6];
  const float* W_attn = (const float*)d_in[7];
  // d_in[8] = b_attn: unused (cancels in softmax over instances)
  const float* W_cls  = (const float*)d_in[9];
  const float* b_cls  = (const float*)d_in[10];
  float* out = (float*)d_out;

  char* ws = (char*)d_ws;
  bf16*  emb    = (bf16*)(ws);                       // 80000*512*2  = 81,920,000 B
  float* logits = (float*)(ws + 81920000);           // 80000*4*4   =  1,280,000 B
  bf16*  WencT  = (bf16*)(ws + 83200000);            // 512*1024*2  =  1,048,576 B
  bf16*  WuT    = (bf16*)(ws + 84248576);            // 512*512*2   =    524,288 B
  bf16*  WvT    = (bf16*)(ws + 84772864);            // 512*512*2   =    524,288 B
  float* sacc   = (float*)(ws + 85297152);           // 32*4        =        128 B

  hipMemsetAsync(logits, 0, 80000 * 4 * sizeof(float), stream);
  hipMemsetAsync(sacc, 0, 32 * sizeof(float), stream);

  transpose_cvt<<<dim3(16, 32), dim3(32, 8), 0, stream>>>(W_enc, WencT, 1024, 512);
  transpose_cvt<<<dim3(16, 16), dim3(32, 8), 0, stream>>>(W_u, WuT, 512, 512);
  transpose_cvt<<<dim3(16, 16), dim3(32, 8), 0, stream>>>(W_v, WvT, 512, 512);

  gemm_enc<<<1250, 512, 0, stream>>>(bags, WencT, b_enc, emb);
  gemm_gate<<<2500, 512, 0, stream>>>(emb, WuT, WvT, b_u, b_v, W_attn, logits);
  softmax_attn<<<32, 256, 0, stream>>>(logits);
  scores_partial<<<dim3(8, 40), 256, 0, stream>>>(emb, logits, W_cls, sacc);
  finalize<<<1, 64, 0, stream>>>(sacc, b_cls, out);
}